// Round 1
// baseline (519.312 us; speedup 1.0000x reference)
//
#include <hip/hip_runtime.h>

typedef unsigned short u16;
typedef __attribute__((ext_vector_type(8))) short bf16x8;   // 8 bf16 = 4 VGPRs
typedef __attribute__((ext_vector_type(4))) float f32x4;

#define TILE 128
#define BK 32

__device__ __forceinline__ void gload16(const void* g, void* l) {
  __builtin_amdgcn_global_load_lds(
      (const __attribute__((address_space(1))) unsigned int*)g,
      (__attribute__((address_space(3))) unsigned int*)l, 16, 0, 0);
}

// Per-row fake-quant: scales[row] = max(absmax,1e-5)/127; q[row][k] = bf16(round(x/scale))
// q values are exact integers in [-127,127] -> exactly representable in bf16.
__global__ __launch_bounds__(256) void quant_rows_kernel(
    const float* __restrict__ src, u16* __restrict__ q,
    float* __restrict__ scales, int K)
{
  const size_t row = blockIdx.x;
  const float* __restrict__ p = src + row * (size_t)K;
  const int t = threadIdx.x;
  const int nv = K >> 2;  // float4 count per row
  float m = 0.0f;
  for (int i = t; i < nv; i += 256) {
    float4 v = ((const float4*)p)[i];
    m = fmaxf(m, fmaxf(fmaxf(fabsf(v.x), fabsf(v.y)),
                       fmaxf(fabsf(v.z), fabsf(v.w))));
  }
  #pragma unroll
  for (int off = 32; off > 0; off >>= 1) m = fmaxf(m, __shfl_xor(m, off));
  __shared__ float wmax[4];
  if ((t & 63) == 0) wmax[t >> 6] = m;
  __syncthreads();
  m = fmaxf(fmaxf(wmax[0], wmax[1]), fmaxf(wmax[2], wmax[3]));
  const float scale = fmaxf(m, 1e-5f) * (1.0f / 127.0f);
  if (t == 0) scales[row] = scale;
  u16* __restrict__ qp = q + row * (size_t)K;
  for (int i = t; i < nv; i += 256) {
    float4 v = ((const float4*)p)[i];   // second read: row fits L1 (16KB)
    ushort4 o;
    o.x = (u16)(__float_as_uint(rintf(v.x / scale)) >> 16);
    o.y = (u16)(__float_as_uint(rintf(v.y / scale)) >> 16);
    o.z = (u16)(__float_as_uint(rintf(v.z / scale)) >> 16);
    o.w = (u16)(__float_as_uint(rintf(v.w / scale)) >> 16);
    ((ushort4*)qp)[i] = o;
  }
}

// C = Aq(MxK) * Bq(NxK)^T, both K-contiguous (bt layout). 128x128 tile, BK=32,
// 4 waves (2x2), each wave 64x64 via 4x4 frags of 16x16x32 bf16 MFMA.
// Epilogue: y = acc*sx[m]*sw[n] + bias[n] -> Y; per-row |y| max -> atomicMax.
__global__ __launch_bounds__(256) void gemm_bt_kernel(
    const u16* __restrict__ Aq, const u16* __restrict__ Bq,
    const float* __restrict__ sx, const float* __restrict__ sw,
    const float* __restrict__ bias, float* __restrict__ Y,
    unsigned int* __restrict__ rowmax, int M, int N, int K)
{
  __shared__ u16 lsA[TILE * BK];
  __shared__ u16 lsB[TILE * BK];

  int bid = (int)blockIdx.x;
  const int nwg = (int)gridDim.x;
  if ((nwg & 7) == 0) {               // XCD-aware swizzle (bijective when nwg%8==0)
    const int cpx = nwg >> 3;
    bid = (bid & 7) * cpx + (bid >> 3);
  }
  const int ntile = N / TILE;
  const size_t brow = (size_t)(bid / ntile) * TILE;
  const size_t bcol = (size_t)(bid % ntile) * TILE;

  const int t = threadIdx.x;
  const int lane = t & 63;
  const int w = t >> 6;
  const int wr = w >> 1, wc = w & 1;   // 2x2 wave grid, each 64x64
  const int g4 = lane >> 4, l16 = lane & 15;

  f32x4 acc[4][4] = {};

  const int nK = K / BK;
  for (int kt = 0; kt < nK; ++kt) {
    // stage A and B tiles: 512 slots x 8 bf16 (16B) each, LDS-linear dest
    #pragma unroll
    for (int r = 0; r < 2; ++r) {
      const int slot = t + r * 256;          // 0..511
      const int rowi = slot >> 2;            // 0..127
      const int col  = (slot & 3) << 3;      // 0,8,16,24
      gload16(Aq + (brow + rowi) * (size_t)K + (size_t)kt * BK + col, &lsA[slot * 8]);
      gload16(Bq + (bcol + rowi) * (size_t)K + (size_t)kt * BK + col, &lsB[slot * 8]);
    }
    __syncthreads();   // compiler emits s_waitcnt vmcnt(0) before barrier

    bf16x8 af[4], bfr[4];
    #pragma unroll
    for (int i = 0; i < 4; ++i)
      af[i] = *(const bf16x8*)&lsA[(wr * 64 + i * 16 + l16) * BK + g4 * 8];
    #pragma unroll
    for (int j = 0; j < 4; ++j)
      bfr[j] = *(const bf16x8*)&lsB[(wc * 64 + j * 16 + l16) * BK + g4 * 8];

    #pragma unroll
    for (int i = 0; i < 4; ++i)
      #pragma unroll
      for (int j = 0; j < 4; ++j)
        acc[i][j] = __builtin_amdgcn_mfma_f32_16x16x32_bf16(af[i], bfr[j], acc[i][j], 0, 0, 0);

    __syncthreads();
  }

  // Epilogue. C/D layout (guide-verified): row=(lane>>4)*4+reg, col=lane&15.
  #pragma unroll
  for (int i = 0; i < 4; ++i) {
    #pragma unroll
    for (int r = 0; r < 4; ++r) {
      const size_t grow = brow + (size_t)(wr * 64 + i * 16 + g4 * 4 + r);
      const float sxr = sx[grow];
      float rmax = 0.0f;
      #pragma unroll
      for (int j = 0; j < 4; ++j) {
        const size_t gcol = bcol + (size_t)(wc * 64 + j * 16 + l16);
        const float y = acc[i][j][r] * (sxr * sw[gcol]) + bias[gcol];
        Y[grow * (size_t)N + gcol] = y;
        rmax = fmaxf(rmax, fabsf(y));
      }
      // reduce across the 16 lanes that share this row
      rmax = fmaxf(rmax, __shfl_xor(rmax, 1));
      rmax = fmaxf(rmax, __shfl_xor(rmax, 2));
      rmax = fmaxf(rmax, __shfl_xor(rmax, 4));
      rmax = fmaxf(rmax, __shfl_xor(rmax, 8));
      if (l16 == 0)
        atomicMax(&rowmax[grow], __float_as_uint(rmax));  // |y|>=0: uint bits order == float order
    }
  }
}

// In-place per-row output fake-quant of Y using rowmax.
__global__ __launch_bounds__(256) void outquant_kernel(
    float* __restrict__ Y, const unsigned int* __restrict__ rowmax, int N)
{
  const size_t row = blockIdx.x;
  const float amax = __uint_as_float(rowmax[row]);
  const float scale = fmaxf(amax, 1e-5f) * (1.0f / 127.0f);
  float* __restrict__ p = Y + row * (size_t)N;
  const int nv = N >> 2;
  for (int i = threadIdx.x; i < nv; i += 256) {
    float4 v = ((float4*)p)[i];
    v.x = rintf(v.x / scale) * scale;
    v.y = rintf(v.y / scale) * scale;
    v.z = rintf(v.z / scale) * scale;
    v.w = rintf(v.w / scale) * scale;
    ((float4*)p)[i] = v;
  }
}

extern "C" void kernel_launch(void* const* d_in, const int* in_sizes, int n_in,
                              void* d_out, int out_size, void* d_ws, size_t ws_size,
                              hipStream_t stream)
{
  const float* x = (const float*)d_in[0];   // [B,S,D_in] fp32
  const float* wgt = (const float*)d_in[1]; // [D_out,D_in] fp32
  const float* bias = (const float*)d_in[2];// [D_out] fp32
  float* out = (float*)d_out;               // [B,S,D_out] fp32 (also used as fp32 scratch for y)

  const int N = in_sizes[2];                // D_out
  const int K = in_sizes[1] / N;            // D_in
  const int M = in_sizes[0] / K;            // B*S

  char* ws = (char*)d_ws;
  u16* qx = (u16*)ws;               ws += (size_t)M * K * sizeof(u16);
  u16* qw = (u16*)ws;               ws += (size_t)N * K * sizeof(u16);
  float* sx = (float*)ws;           ws += (size_t)M * sizeof(float);
  float* sw = (float*)ws;           ws += (size_t)N * sizeof(float);
  unsigned int* rowmax = (unsigned int*)ws;

  hipMemsetAsync(rowmax, 0, (size_t)M * sizeof(unsigned int), stream);

  quant_rows_kernel<<<M, 256, 0, stream>>>(x, qx, sx, K);
  quant_rows_kernel<<<N, 256, 0, stream>>>(wgt, qw, sw, K);

  const int grid = (M / TILE) * (N / TILE);
  gemm_bt_kernel<<<grid, 256, 0, stream>>>(qx, qw, sx, sw, bias, out, rowmax, M, N, K);

  outquant_kernel<<<M, 256, 0, stream>>>(out, rowmax, N);
}

// Round 2
// 382.531 us; speedup vs baseline: 1.3576x; 1.3576x over previous
//
#include <hip/hip_runtime.h>

typedef unsigned short u16;
typedef __attribute__((ext_vector_type(8))) short bf16x8;   // 8 bf16 = 4 VGPRs
typedef __attribute__((ext_vector_type(4))) float f32x4;

#define BM 256
#define BN 256
#define BKT 64

__device__ __forceinline__ void gload16(const void* g, void* l) {
  __builtin_amdgcn_global_load_lds(
      (const __attribute__((address_space(1))) unsigned int*)g,
      (__attribute__((address_space(3))) unsigned int*)l, 16, 0, 0);
}

// ---------------- per-row fake-quant (unchanged from R1) ----------------
__global__ __launch_bounds__(256) void quant_rows_kernel(
    const float* __restrict__ src, u16* __restrict__ q,
    float* __restrict__ scales, int K)
{
  const size_t row = blockIdx.x;
  const float* __restrict__ p = src + row * (size_t)K;
  const int t = threadIdx.x;
  const int nv = K >> 2;
  float m = 0.0f;
  for (int i = t; i < nv; i += 256) {
    float4 v = ((const float4*)p)[i];
    m = fmaxf(m, fmaxf(fmaxf(fabsf(v.x), fabsf(v.y)),
                       fmaxf(fabsf(v.z), fabsf(v.w))));
  }
  #pragma unroll
  for (int off = 32; off > 0; off >>= 1) m = fmaxf(m, __shfl_xor(m, off));
  __shared__ float wmax[4];
  if ((t & 63) == 0) wmax[t >> 6] = m;
  __syncthreads();
  m = fmaxf(fmaxf(wmax[0], wmax[1]), fmaxf(wmax[2], wmax[3]));
  const float scale = fmaxf(m, 1e-5f) * (1.0f / 127.0f);
  if (t == 0) scales[row] = scale;
  u16* __restrict__ qp = q + row * (size_t)K;
  for (int i = t; i < nv; i += 256) {
    float4 v = ((const float4*)p)[i];
    ushort4 o;
    o.x = (u16)(__float_as_uint(rintf(v.x / scale)) >> 16);
    o.y = (u16)(__float_as_uint(rintf(v.y / scale)) >> 16);
    o.z = (u16)(__float_as_uint(rintf(v.z / scale)) >> 16);
    o.w = (u16)(__float_as_uint(rintf(v.w / scale)) >> 16);
    ((ushort4*)qp)[i] = o;
  }
}

// ---------------- 256x256 8-wave 4-phase GEMM, counted vmcnt ----------------
// C = Aq(MxK) * Bq(NxK)^T. LDS: 2 slots x (A 256x64 + B 256x64) bf16 = 128 KiB.
// Swizzle: LDS (row, slot16) holds global (row, slot16 ^ (row&7)); involution,
// applied on the global SOURCE at staging (LDS dest stays linear for
// global_load_lds) and on the ds_read address.
__global__ __launch_bounds__(512, 2) void gemm_bt_kernel(
    const u16* __restrict__ Aq, const u16* __restrict__ Bq,
    const float* __restrict__ sx, const float* __restrict__ sw,
    const float* __restrict__ bias, float* __restrict__ Y,
    unsigned int* __restrict__ rowmax, int M, int N, int K)
{
  __shared__ u16 lds[2][2][BM * BKT];   // [slot][A/B][256*64] = 128 KiB

  int bid = (int)blockIdx.x;
  const int nwg = (int)gridDim.x;
  if ((nwg & 7) == 0) {                 // bijective XCD swizzle (nwg%8==0)
    const int cpx = nwg >> 3;
    bid = (bid & 7) * cpx + (bid >> 3);
  }
  const int ntile = N / BN;
  const size_t brow = (size_t)(bid / ntile) * BM;
  const size_t bcol = (size_t)(bid % ntile) * BN;

  const int t = threadIdx.x;
  const int lane = t & 63;
  const int wid = t >> 6;
  const int wr = wid >> 2, wc = wid & 3;       // 2(M) x 4(N) wave grid
  const int g4 = lane >> 4, l16 = lane & 15, l7 = lane & 7;

  // staging: thread covers row tr (of a 64-row round) and 16B slot ts.
  // pre-swizzled source slot so linear LDS dest ends up swizzled.
  const int tr = t >> 3, ts = t & 7;
  const int sslot = ts ^ (tr & 7);
  const u16* srcA = Aq + (brow + tr) * (size_t)K + sslot * 8;
  const u16* srcB = Bq + (bcol + tr) * (size_t)K + sslot * 8;
  const int dst = t * 8;                        // u16 offset within a round

  f32x4 acc[2][4][4] = {};
  const int nK = K / BKT;

#define STA(s, r, tt) gload16(srcA + ((size_t)(r) * 64) * (size_t)K + (size_t)(tt) * BKT, \
                              &lds[s][0][(r) * 4096 + dst])
#define STB(s, r, tt) gload16(srcB + ((size_t)(r) * 64) * (size_t)K + (size_t)(tt) * BKT, \
                              &lds[s][1][(r) * 4096 + dst])

#define BARS() do { __builtin_amdgcn_s_barrier(); \
                    __builtin_amdgcn_sched_barrier(0); \
                    asm volatile("" ::: "memory"); } while (0)

#define LOADB(s, ks) do { \
    const u16* pb_ = &lds[s][1][(wc * 64 + l16) * 64 + ((((ks) * 4 + g4) ^ l7) * 8)]; \
    vb0 = *(const bf16x8*)(pb_); \
    vb1 = *(const bf16x8*)(pb_ + 1024); \
    vb2 = *(const bf16x8*)(pb_ + 2048); \
    vb3 = *(const bf16x8*)(pb_ + 3072); \
  } while (0)

#define ROW(mh, i, a_) \
    acc[mh][i][0] = __builtin_amdgcn_mfma_f32_16x16x32_bf16(a_, vb0, acc[mh][i][0], 0, 0, 0); \
    acc[mh][i][1] = __builtin_amdgcn_mfma_f32_16x16x32_bf16(a_, vb1, acc[mh][i][1], 0, 0, 0); \
    acc[mh][i][2] = __builtin_amdgcn_mfma_f32_16x16x32_bf16(a_, vb2, acc[mh][i][2], 0, 0, 0); \
    acc[mh][i][3] = __builtin_amdgcn_mfma_f32_16x16x32_bf16(a_, vb3, acc[mh][i][3], 0, 0, 0);

#define PHASE(s, mh, ks) do { \
    const u16* pa_ = &lds[s][0][(wr * 128 + (mh) * 64 + l16) * 64 + ((((ks) * 4 + g4) ^ l7) * 8)]; \
    bf16x8 a0_ = *(const bf16x8*)(pa_); \
    bf16x8 a1_ = *(const bf16x8*)(pa_ + 1024); \
    bf16x8 a2_ = *(const bf16x8*)(pa_ + 2048); \
    bf16x8 a3_ = *(const bf16x8*)(pa_ + 3072); \
    __builtin_amdgcn_s_setprio(1); \
    ROW(mh, 0, a0_) \
    ROW(mh, 1, a1_) \
    ROW(mh, 2, a2_) \
    ROW(mh, 3, a3_) \
    __builtin_amdgcn_s_setprio(0); \
  } while (0)

  // prologue: stage tile 0 into slot 0; order matters for counted vmcnt:
  // [A0,A2,B0,B1,B2,B3,A1,A3] — needed-at-phase-1 rounds first.
  STA(0, 0, 0); STA(0, 2, 0); STB(0, 0, 0); STB(0, 1, 0);
  STB(0, 2, 0); STB(0, 3, 0); STA(0, 1, 0); STA(0, 3, 0);

  bf16x8 vb0, vb1, vb2, vb3;

  for (int kt = 0; kt < nK - 1; ++kt) {
    const int s = kt & 1, sn = s ^ 1;
    // --- phase 1: ks=0, m-half 0. needs tile-kt rounds A0,A2,B0..B3 (oldest 6)
    STA(sn, 0, kt + 1); STA(sn, 2, kt + 1); STB(sn, 0, kt + 1); STB(sn, 1, kt + 1);
    asm volatile("s_waitcnt vmcnt(6)" ::: "memory");
    BARS();
    LOADB(s, 0);
    PHASE(s, 0, 0);
    // --- phase 2: ks=0, m-half 1. needs tile-kt rounds A1,A3
    STB(sn, 2, kt + 1); STB(sn, 3, kt + 1); STA(sn, 1, kt + 1); STA(sn, 3, kt + 1);
    asm volatile("s_waitcnt vmcnt(8)" ::: "memory");
    BARS();
    PHASE(s, 1, 0);
    // --- phase 3: ks=1, m-half 0 (pacing barrier only)
    BARS();
    LOADB(s, 1);
    PHASE(s, 0, 1);
    // --- phase 4: ks=1, m-half 1
    BARS();
    PHASE(s, 1, 1);
    // WAR barrier: slot s fully read; next iter stages into slot s
    BARS();
  }

  // peeled last K-tile (no staging; drain allowed here)
  {
    const int s = (nK - 1) & 1;
    asm volatile("s_waitcnt vmcnt(2)" ::: "memory");
    BARS();
    LOADB(s, 0);
    PHASE(s, 0, 0);
    asm volatile("s_waitcnt vmcnt(0)" ::: "memory");
    BARS();
    PHASE(s, 1, 0);
    BARS();
    LOADB(s, 1);
    PHASE(s, 0, 1);
    BARS();
    PHASE(s, 1, 1);
  }

  // ---------------- epilogue: scale + bias, store Y, per-row |y| max ----------------
  float swv[4], biv[4];
  size_t gcolv[4];
  #pragma unroll
  for (int j = 0; j < 4; ++j) {
    gcolv[j] = bcol + wc * 64 + j * 16 + l16;
    swv[j] = sw[gcolv[j]];
    biv[j] = bias[gcolv[j]];
  }
  #pragma unroll
  for (int mh = 0; mh < 2; ++mh) {
    #pragma unroll
    for (int i = 0; i < 4; ++i) {
      #pragma unroll
      for (int r = 0; r < 4; ++r) {
        const size_t grow = brow + (size_t)(wr * 128 + mh * 64 + i * 16 + g4 * 4 + r);
        const float sxr = sx[grow];
        float* yrow = Y + grow * (size_t)N;
        float rmax = 0.0f;
        #pragma unroll
        for (int j = 0; j < 4; ++j) {
          const float y = acc[mh][i][j][r] * (sxr * swv[j]) + biv[j];
          yrow[gcolv[j]] = y;
          rmax = fmaxf(rmax, fabsf(y));
        }
        rmax = fmaxf(rmax, __shfl_xor(rmax, 1));
        rmax = fmaxf(rmax, __shfl_xor(rmax, 2));
        rmax = fmaxf(rmax, __shfl_xor(rmax, 4));
        rmax = fmaxf(rmax, __shfl_xor(rmax, 8));
        if (l16 == 0)
          atomicMax(&rowmax[grow], __float_as_uint(rmax));
      }
    }
  }
#undef STA
#undef STB
#undef BARS
#undef LOADB
#undef ROW
#undef PHASE
}

// ---------------- in-place per-row output fake-quant ----------------
__global__ __launch_bounds__(256) void outquant_kernel(
    float* __restrict__ Y, const unsigned int* __restrict__ rowmax, int N)
{
  const size_t row = blockIdx.x;
  const float amax = __uint_as_float(rowmax[row]);
  const float scale = fmaxf(amax, 1e-5f) * (1.0f / 127.0f);
  float* __restrict__ p = Y + row * (size_t)N;
  const int nv = N >> 2;
  for (int i = threadIdx.x; i < nv; i += 256) {
    float4 v = ((float4*)p)[i];
    v.x = rintf(v.x / scale) * scale;
    v.y = rintf(v.y / scale) * scale;
    v.z = rintf(v.z / scale) * scale;
    v.w = rintf(v.w / scale) * scale;
    ((float4*)p)[i] = v;
  }
}

extern "C" void kernel_launch(void* const* d_in, const int* in_sizes, int n_in,
                              void* d_out, int out_size, void* d_ws, size_t ws_size,
                              hipStream_t stream)
{
  const float* x = (const float*)d_in[0];   // [B,S,D_in] fp32
  const float* wgt = (const float*)d_in[1]; // [D_out,D_in] fp32
  const float* bias = (const float*)d_in[2];// [D_out] fp32
  float* out = (float*)d_out;               // [B,S,D_out] fp32

  const int N = in_sizes[2];                // D_out
  const int K = in_sizes[1] / N;            // D_in
  const int M = in_sizes[0] / K;            // B*S

  char* ws = (char*)d_ws;
  u16* qx = (u16*)ws;               ws += (size_t)M * K * sizeof(u16);
  u16* qw = (u16*)ws;               ws += (size_t)N * K * sizeof(u16);
  float* sx = (float*)ws;           ws += (size_t)M * sizeof(float);
  float* sw = (float*)ws;           ws += (size_t)N * sizeof(float);
  unsigned int* rowmax = (unsigned int*)ws;

  hipMemsetAsync(rowmax, 0, (size_t)M * sizeof(unsigned int), stream);

  quant_rows_kernel<<<M, 256, 0, stream>>>(x, qx, sx, K);
  quant_rows_kernel<<<N, 256, 0, stream>>>(wgt, qw, sw, K);

  const int grid = (M / BM) * (N / BN);
  gemm_bt_kernel<<<grid, 512, 0, stream>>>(qx, qw, sx, sw, bias, out, rowmax, M, N, K);

  outquant_kernel<<<M, 256, 0, stream>>>(out, rowmax, N);
}